// Round 2
// baseline (24001.764 us; speedup 1.0000x reference)
//
#include <hip/hip_runtime.h>
#include <hip/hip_bf16.h>

#define V_  32000
#define C_  512
#define H_  8
#define L_  6
#define D_  64
#define B_  2
#define T_  2048
#define M_  (B_*T_)
#define EPS_ 1e-5f

typedef unsigned short u16;

__device__ __forceinline__ float bf2f(u16 u) {
    return __uint_as_float(((unsigned int)u) << 16);
}
__device__ __forceinline__ u16 f2bf(float f) {
    unsigned int u = __float_as_uint(f);
    unsigned int r = u + 0x7fffu + ((u >> 16) & 1u);
    return (u16)(r >> 16);
}
// Dtype probe: ln1_w[0][0] == 1.0f. bf16 -> u16[0]==0x3F80 ; fp32 -> 0x0000.
__device__ __forceinline__ bool is_bf(const u16* probe) { return probe[0] == 0x3F80u; }
__device__ __forceinline__ float ldf(const void* p, size_t i, bool isbf) {
    return isbf ? bf2f(((const u16*)p)[i]) : ((const float*)p)[i];
}

// ---------------------------------------------------------------- embedding
__global__ __launch_bounds__(256) void embed_kernel(
    const int* __restrict__ idx, const void* __restrict__ tok,
    const void* __restrict__ pos, float* __restrict__ x,
    const u16* __restrict__ probe)
{
    bool isbf = is_bf(probe);
    int i = blockIdx.x * 256 + threadIdx.x;
    if (i >= M_*C_) return;
    int c  = i & (C_-1);
    int bt = i >> 9;
    int t  = bt & (T_-1);
    int token = idx[bt];
    x[i] = ldf(tok, (size_t)token*C_ + c, isbf) + ldf(pos, (size_t)t*C_ + c, isbf);
}

// ---------------------------------------------------------------- layernorm
__global__ __launch_bounds__(256) void ln_kernel(
    const float* __restrict__ x, const void* __restrict__ w,
    const void* __restrict__ b, size_t wb_off, float* __restrict__ out,
    const u16* __restrict__ probe)
{
    bool isbf = is_bf(probe);
    int row = blockIdx.x;
    int t = threadIdx.x;
    const float* xr = x + (size_t)row*C_;
    float v0 = xr[t], v1 = xr[t + 256];
    __shared__ float red[256];
    red[t] = v0 + v1; __syncthreads();
    for (int off = 128; off > 0; off >>= 1) { if (t < off) red[t] += red[t+off]; __syncthreads(); }
    float mu = red[0] * (1.0f/C_);
    __syncthreads();
    float d0 = v0 - mu, d1 = v1 - mu;
    red[t] = d0*d0 + d1*d1; __syncthreads();
    for (int off = 128; off > 0; off >>= 1) { if (t < off) red[t] += red[t+off]; __syncthreads(); }
    float rs = rsqrtf(red[0] * (1.0f/C_) + EPS_);
    out[(size_t)row*C_ + t]       = d0*rs*ldf(w, wb_off+t, isbf)     + ldf(b, wb_off+t, isbf);
    out[(size_t)row*C_ + t + 256] = d1*rs*ldf(w, wb_off+t+256, isbf) + ldf(b, wb_off+t+256, isbf);
}

// ---------------------------------------------------------------- GEMM
// out[M,N] = A[M,K](fp32) . W[N,K]^T + bias
// mode 0: fp32 store | 1: gelu fp32 | 2: outF += | 3: store to outRaw per probe dtype
#define BM 64
#define BN 64
#define BK 16
__global__ __launch_bounds__(256) void gemm_kernel(
    const float* __restrict__ A, const void* __restrict__ W, size_t w_off,
    const void* __restrict__ bias, size_t b_off,
    float* __restrict__ outF, void* __restrict__ outRaw,
    int M, int N, int K, int mode, const u16* __restrict__ probe)
{
    bool isbf = is_bf(probe);
    __shared__ float As[BK][BM+1];
    __shared__ float Ws[BK][BN+1];
    int t  = threadIdx.x;
    int tx = t & 15, ty = t >> 4;
    int m0 = blockIdx.y * BM, n0 = blockIdx.x * BN;
    int lr = t >> 2;
    int lc = (t & 3) * 4;
    float acc[4][4] = {};
    for (int k0 = 0; k0 < K; k0 += BK) {
        float4 av = *(const float4*)(A + (size_t)(m0 + lr)*K + k0 + lc);
        As[lc+0][lr] = av.x; As[lc+1][lr] = av.y;
        As[lc+2][lr] = av.z; As[lc+3][lr] = av.w;
        size_t wi = w_off + (size_t)(n0 + lr)*K + k0 + lc;
        if (isbf) {
            ushort4 wv = *(const ushort4*)((const u16*)W + wi);
            Ws[lc+0][lr] = bf2f(wv.x); Ws[lc+1][lr] = bf2f(wv.y);
            Ws[lc+2][lr] = bf2f(wv.z); Ws[lc+3][lr] = bf2f(wv.w);
        } else {
            float4 wv = *(const float4*)((const float*)W + wi);
            Ws[lc+0][lr] = wv.x; Ws[lc+1][lr] = wv.y;
            Ws[lc+2][lr] = wv.z; Ws[lc+3][lr] = wv.w;
        }
        __syncthreads();
        #pragma unroll
        for (int kk = 0; kk < BK; kk++) {
            float a[4], w[4];
            #pragma unroll
            for (int i = 0; i < 4; i++) a[i] = As[kk][ty*4+i];
            #pragma unroll
            for (int j = 0; j < 4; j++) w[j] = Ws[kk][tx*4+j];
            #pragma unroll
            for (int i = 0; i < 4; i++)
                #pragma unroll
                for (int j = 0; j < 4; j++)
                    acc[i][j] += a[i]*w[j];
        }
        __syncthreads();
    }
    #pragma unroll
    for (int i = 0; i < 4; i++) {
        int m = m0 + ty*4 + i;
        #pragma unroll
        for (int j = 0; j < 4; j++) {
            int n = n0 + tx*4 + j;
            float v = acc[i][j] + ldf(bias, b_off + n, isbf);
            if (mode == 1) v = 0.5f * v * (1.0f + erff(v * 0.70710678118f));
            size_t o = (size_t)m*N + n;
            if (mode == 2)      outF[o] += v;
            else if (mode == 3) { if (isbf) ((u16*)outRaw)[o] = f2bf(v); else ((float*)outRaw)[o] = v; }
            else                outF[o] = v;
        }
    }
}

// ---------------------------------------------------------------- attention
__global__ __launch_bounds__(256) void attn_kernel(
    const float* __restrict__ qkv, float* __restrict__ out)
{
    __shared__ float sc[T_];
    __shared__ float qrow[D_];
    __shared__ float red[256];
    __shared__ float op[4][D_];
    int q  = blockIdx.x;
    int bh = blockIdx.y;
    int b = bh >> 3, h = bh & 7;
    int t = threadIdx.x;
    const float* qptr = qkv + (size_t)(b*T_ + q)*(3*C_) + h*D_;
    if (t < D_) qrow[t] = qptr[t];
    __syncthreads();
    int nk = q + 1;
    const float* kbase = qkv + (size_t)b*T_*3*C_ + C_ + h*D_;
    for (int k = t; k < nk; k += 256) {
        const float* kp = kbase + (size_t)k*3*C_;
        float s = 0.f;
        #pragma unroll
        for (int d = 0; d < D_; d++) s += qrow[d]*kp[d];
        sc[k] = s * 0.125f;
    }
    __syncthreads();
    float lm = -1e30f;
    for (int k = t; k < nk; k += 256) lm = fmaxf(lm, sc[k]);
    red[t] = lm; __syncthreads();
    for (int off = 128; off > 0; off >>= 1) { if (t < off) red[t] = fmaxf(red[t], red[t+off]); __syncthreads(); }
    float m = red[0];
    __syncthreads();
    float ls = 0.f;
    for (int k = t; k < nk; k += 256) { float p = __expf(sc[k]-m); sc[k] = p; ls += p; }
    red[t] = ls; __syncthreads();
    for (int off = 128; off > 0; off >>= 1) { if (t < off) red[t] += red[t+off]; __syncthreads(); }
    float l = red[0];
    __syncthreads();
    int g = t >> 6;
    int d = t & 63;
    const float* vbase = qkv + (size_t)b*T_*3*C_ + 2*C_ + h*D_ + d;
    float partial = 0.f;
    for (int k = g; k < nk; k += 4) partial += sc[k] * vbase[(size_t)k*3*C_];
    op[g][d] = partial;
    __syncthreads();
    if (g == 0) {
        float o = (op[0][d] + op[1][d] + op[2][d] + op[3][d]) / l;
        out[(size_t)(b*T_ + q)*C_ + h*D_ + d] = o;
    }
}

// ---------------------------------------------------------------- loss
__global__ void zero_kernel(float* a) { if (threadIdx.x == 0 && blockIdx.x == 0) a[0] = 0.f; }

__global__ __launch_bounds__(256) void nll_kernel(
    const void* __restrict__ logits, const int* __restrict__ targets, float* accum,
    const u16* __restrict__ probe)
{
    bool isbf = is_bf(probe);
    int row = blockIdx.x;
    size_t base = (size_t)row * V_;
    int t = threadIdx.x;
    __shared__ float red[256];
    float lm = -1e30f;
    for (int v = t; v < V_; v += 256) lm = fmaxf(lm, ldf(logits, base + v, isbf));
    red[t] = lm; __syncthreads();
    for (int off = 128; off > 0; off >>= 1) { if (t < off) red[t] = fmaxf(red[t], red[t+off]); __syncthreads(); }
    float m = red[0];
    __syncthreads();
    float ls = 0.f;
    for (int v = t; v < V_; v += 256) ls += __expf(ldf(logits, base + v, isbf) - m);
    red[t] = ls; __syncthreads();
    for (int off = 128; off > 0; off >>= 1) { if (t < off) red[t] += red[t+off]; __syncthreads(); }
    if (t == 0) {
        float lse = m + logf(red[0]);
        float nll = lse - ldf(logits, base + targets[row], isbf);
        atomicAdd(accum, nll);
    }
}

__global__ void finalize_kernel(const float* a, void* out, const u16* probe) {
    if (threadIdx.x == 0 && blockIdx.x == 0) {
        float loss = a[0] / (float)M_;
        if (is_bf(probe)) ((u16*)out)[(size_t)M_*V_] = f2bf(loss);
        else              ((float*)out)[(size_t)M_*V_] = loss;
    }
}

// ---------------------------------------------------------------- launch
extern "C" void kernel_launch(void* const* d_in, const int* in_sizes, int n_in,
                              void* d_out, int out_size, void* d_ws, size_t ws_size,
                              hipStream_t stream)
{
    const int* idx     = (const int*)d_in[0];
    const int* targets = (const int*)d_in[1];
    const u16* probe   = (const u16*)d_in[8];   // ln1_w, all-ones

    float* ws    = (float*)d_ws;
    float* x     = ws;                          // M*C
    float* xn    = x   + (size_t)M_*C_;         // M*C
    float* big   = xn  + (size_t)M_*C_;         // M*4C (qkv overlaid with h1)
    float* qkv   = big;
    float* h1    = big;
    float* accum = big + (size_t)M_*4*C_;       // ~50.3 MB total

    embed_kernel<<<(M_*C_ + 255)/256, 256, 0, stream>>>(idx, d_in[2], d_in[3], x, probe);

    for (int l = 0; l < L_; l++) {
        size_t o_ln = (size_t)l*C_;
        ln_kernel<<<M_, 256, 0, stream>>>(x, d_in[8], d_in[9], o_ln, xn, probe);
        gemm_kernel<<<dim3(3*C_/BN, M_/BM), 256, 0, stream>>>(
            xn, d_in[4], (size_t)l*3*C_*C_, d_in[5], (size_t)l*3*C_,
            qkv, nullptr, M_, 3*C_, C_, 0, probe);
        attn_kernel<<<dim3(T_, B_*H_), 256, 0, stream>>>(qkv, xn);
        gemm_kernel<<<dim3(C_/BN, M_/BM), 256, 0, stream>>>(
            xn, d_in[6], (size_t)l*C_*C_, d_in[7], (size_t)l*C_,
            x, nullptr, M_, C_, C_, 2, probe);
        ln_kernel<<<M_, 256, 0, stream>>>(x, d_in[14], d_in[15], o_ln, xn, probe);
        gemm_kernel<<<dim3(4*C_/BN, M_/BM), 256, 0, stream>>>(
            xn, d_in[10], (size_t)l*4*C_*C_, d_in[11], (size_t)l*4*C_,
            h1, nullptr, M_, 4*C_, C_, 1, probe);
        gemm_kernel<<<dim3(C_/BN, M_/BM), 256, 0, stream>>>(
            h1, d_in[12], (size_t)l*C_*4*C_, d_in[13], (size_t)l*C_,
            x, nullptr, M_, C_, 4*C_, 2, probe);
    }

    ln_kernel<<<M_, 256, 0, stream>>>(x, d_in[16], d_in[17], 0, xn, probe);
    gemm_kernel<<<dim3(V_/BN, M_/BM), 256, 0, stream>>>(
        xn, d_in[18], 0, d_in[19], 0, nullptr, d_out, M_, V_, C_, 3, probe);

    zero_kernel<<<1, 64, 0, stream>>>(accum);
    nll_kernel<<<M_, 256, 0, stream>>>(d_out, targets, accum, probe);
    finalize_kernel<<<1, 64, 0, stream>>>(accum, d_out, probe);
}